// Round 3
// baseline (10.141 us; speedup 1.0000x reference)
//
#include <hip/hip_runtime.h>
#include <hip/hip_bf16.h>

// Bruxism frame judgement: 512 scores -> (judgement, value).
// Single-wave kernel, zero LDS, zero barriers, zero cross-lane shuffles:
//  - ranks of the 3 non-brux classes via ballot + scalar popcount
//  - combo range checks from uniform (scalar-pipe) loads
//  - round(x*100)/100 folded to compile-time constants (identity in f32
//    for every table entry; hand-verified per-entry)

#define N_COMBOS 13

__global__ __launch_bounds__(64)
void bruxism_judge_kernel(const float* __restrict__ score, float* __restrict__ out) {
    const int t = threadIdx.x;  // 0..63

    // Lane t holds elems [4t..4t+3] and [256+4t..256+4t+3] -> all 512 covered.
    const float4 a = reinterpret_cast<const float4*>(score)[t];
    const float4 b = reinterpret_cast<const float4*>(score)[64 + t];
    const float v[8] = {a.x, a.y, a.z, a.w, b.x, b.y, b.z, b.w};

    // Non-brux reference values: uniform address -> scalar loads, broadcast.
    const float s38 = score[38];
    const float s42 = score[42];
    const float s0  = score[0];

    // rank(c) = #{j : s[j] > s[c]} + #{j : s[j]==s[c] && j < c}  (lax.top_k
    // stable tie-break). In top-10 iff rank < 10. ballot -> scalar popcount:
    // no shuffle dep chain, results wave-uniform in SGPRs.
    int cnt38 = 0, cnt42 = 0, cnt0 = 0;
    #pragma unroll
    for (int e = 0; e < 8; ++e) {
        const float x = v[e];
        const int   j = (e < 4) ? (4 * t + e) : (256 + 4 * t + (e - 4));
        cnt38 += __popcll(__ballot((x > s38) || ((x == s38) && (j < 38))));
        cnt42 += __popcll(__ballot((x > s42) || ((x == s42) && (j < 42))));
        cnt0  += __popcll(__ballot( x > s0 ));   // ties need j<0: impossible
    }
    const bool has_non_brux = (cnt38 < 10) || (cnt42 < 10) || (cnt0 < 10);

    // Combo tables. Class values come from uniform scalar loads (s_load),
    // issued on the scalar memory pipe in parallel with the vector loads.
    constexpr int cls[N_COMBOS][3] = {
        {500,  41,   0}, {369, 500,   0}, {412, 431, 470}, {127,  67, 103},
        {399, 403, 412}, {410, 411, 398}, {412, 410, 398}, {435, 438, 449},
        {374, 436, 435}, {372, 434, 469}, {500, 439,  50}, {399, 403, 410},
        {410, 398, 435},
    };
    constexpr float cmin[N_COMBOS][3] = {
        {0.10f, 0.05f, 0.00f}, {0.10f, 0.10f, 0.00f}, {0.05f, 0.05f, 0.05f},
        {0.10f, 0.10f, 0.10f}, {0.10f, 0.10f, 0.10f}, {0.10f, 0.10f, 0.10f},
        {0.10f, 0.10f, 0.10f}, {0.10f, 0.10f, 0.10f}, {0.10f, 0.10f, 0.10f},
        {0.10f, 0.10f, 0.10f}, {0.10f, 0.10f, 0.10f}, {0.10f, 0.10f, 0.10f},
        {0.10f, 0.10f, 0.10f},
    };
    constexpr float cmax[N_COMBOS][3] = {
        {0.8f, 0.5f, 1.0f}, {0.5f, 0.5f, 1.0f}, {0.4f, 0.4f, 0.4f},
        {0.8f, 0.7f, 0.6f}, {0.9f, 0.8f, 0.7f}, {0.9f, 0.8f, 0.7f},
        {0.8f, 0.7f, 0.6f}, {0.9f, 0.8f, 0.7f}, {0.9f, 0.8f, 0.7f},
        {0.9f, 0.8f, 0.7f}, {0.8f, 0.7f, 0.6f}, {0.9f, 0.8f, 0.7f},
        {0.9f, 0.8f, 0.7f},
    };
    // value = round(brux*100)/100 precomputed: identity in f32 for all rows.
    constexpr float bval[N_COMBOS] = {
        294.0f / 100.0f, 176.0f / 100.0f, 176.0f / 100.0f, 147.0f / 100.0f,
         29.0f / 100.0f,  88.0f / 100.0f,   1.0f / 100.0f,  29.0f / 100.0f,
         29.0f / 100.0f,   1.0f / 100.0f,  29.0f / 100.0f,   1.0f / 100.0f,
          1.0f / 100.0f,
    };

    bool  any_pass = false;
    float value_if = bval[0];
    #pragma unroll
    for (int i = N_COMBOS - 1; i >= 0; --i) {
        bool pass = true;
        #pragma unroll
        for (int j = 0; j < 3; ++j) {
            const float val = score[cls[i][j]];   // uniform -> s_load
            pass = pass && (val >= cmin[i][j]) && (val <= cmax[i][j]);
        }
        if (pass) { any_pass = true; value_if = bval[i]; }
    }

    if (t == 0) {
        const bool judgement = any_pass && !has_non_brux;
        float2 o = make_float2(judgement ? 1.0f : 0.0f,
                               judgement ? value_if : 0.0f);
        *reinterpret_cast<float2*>(out) = o;
    }
}

extern "C" void kernel_launch(void* const* d_in, const int* in_sizes, int n_in,
                              void* d_out, int out_size, void* d_ws, size_t ws_size,
                              hipStream_t stream) {
    const float* score = (const float*)d_in[0];
    float* out = (float*)d_out;
    bruxism_judge_kernel<<<1, 64, 0, stream>>>(score, out);
}